// Round 6
// baseline (259.421 us; speedup 1.0000x reference)
//
#include <hip/hip_runtime.h>

#define N_IMG 4
#define E_DIM 16
#define P_PIX 320000
#define G_PIX (P_PIX / 4)     // 80000 float4 groups per image
#define C_CLS 20
#define CK 19                 // classes 1..19 (IGNORE = 0 excluded)
#define MSTRIDE 17            // mean-tile stride: 17 invertible mod 32
#define CSTR 3                // class stride in accumulator LDS: 3 invertible mod 32

// ws layout (floats): sums[n][c][e], counts[n][c], means[n][c][e], loss
#define SUMS_OFF 0
#define CNT_OFF  (N_IMG * C_CLS * E_DIM)            // 1280
#define MEAN_OFF (CNT_OFF + N_IMG * C_CLS)          // 1360
#define LOSS_OFF (MEAN_OFF + N_IMG * C_CLS * E_DIM) // 2640
#define WS_FLOATS (LOSS_OFF + 1)

// ---------------- Kernel 1: per-class sums + counts (pixel-major) ----------------
// One float4-group per thread; all 17 loads forced to issue BEFORE any consumer
// via sched_barrier(0) (rounds 2/4/5: without it the scheduler sinks loads to
// their atomic consumers -> VGPR 16-36, serialized latency, ~120 us).
__global__ __launch_bounds__(256, 2) void k_sums(const float* __restrict__ emb,
                                                 const int* __restrict__ target,
                                                 float* __restrict__ ws) {
    __shared__ float lsum[E_DIM * 64];   // [e][c*3+rep], 4 KB
    __shared__ float lcnt[64];
    const int n = blockIdx.y;
    const int tid = threadIdx.x;
    const int rep = tid & 1;

    for (int i = tid; i < E_DIM * 64; i += 256) lsum[i] = 0.f;
    if (tid < 64) lcnt[tid] = 0.f;
    __syncthreads();

    const int g = blockIdx.x * 256 + tid;
    if (g < G_PIX) {
        const int4 lb = ((const int4*)target)[(size_t)n * G_PIX + g];
        const float4* emb4 = (const float4*)emb + (size_t)n * E_DIM * G_PIX;
        float4 v[E_DIM];
#pragma unroll
        for (int e = 0; e < E_DIM; e++) v[e] = emb4[(size_t)e * G_PIX + g];

        __builtin_amdgcn_sched_barrier(0);   // no instr may cross: all loads issue first

        const int ax = lb.x * CSTR + rep, ay = lb.y * CSTR + rep;
        const int az = lb.z * CSTR + rep, aw = lb.w * CSTR + rep;
        atomicAdd(&lcnt[ax], 1.f);
        atomicAdd(&lcnt[ay], 1.f);
        atomicAdd(&lcnt[az], 1.f);
        atomicAdd(&lcnt[aw], 1.f);
#pragma unroll
        for (int e = 0; e < E_DIM; e++) {
            atomicAdd(&lsum[e * 64 + ax], v[e].x);
            atomicAdd(&lsum[e * 64 + ay], v[e].y);
            atomicAdd(&lsum[e * 64 + az], v[e].z);
            atomicAdd(&lsum[e * 64 + aw], v[e].w);
        }
    }
    __syncthreads();

    for (int i = tid; i < C_CLS * E_DIM; i += 256) {
        const int c = i >> 4, e = i & 15;
        const float s = lsum[e * 64 + c * CSTR] + lsum[e * 64 + c * CSTR + 1];
        atomicAdd(ws + SUMS_OFF + (size_t)(n * C_CLS + c) * E_DIM + e, s);
    }
    if (tid < C_CLS) {
        atomicAdd(ws + CNT_OFF + n * C_CLS + tid, lcnt[tid * CSTR] + lcnt[tid * CSTR + 1]);
    }
}

// -------- Kernel 2: means + distance(push) term + regularizer --------
__global__ void k_means_dist(float* __restrict__ ws) {
    __shared__ float lmean[C_CLS * E_DIM];
    __shared__ float red[256];
    const int n = blockIdx.x, tid = threadIdx.x;

    const float* gsum = ws + SUMS_OFF + n * C_CLS * E_DIM;
    const float* gcnt = ws + CNT_OFF + n * C_CLS;
    float* gmean = ws + MEAN_OFF + n * C_CLS * E_DIM;

    for (int i = tid; i < C_CLS * E_DIM; i += blockDim.x) {
        const int c = i / E_DIM;
        const float cnt = gcnt[c];
        const float m = (cnt > 0.f) ? gsum[i] / cnt : 0.f;
        lmean[i] = m;
        gmean[i] = m;
    }
    __syncthreads();

    float acc = 0.f;
    for (int idx = tid; idx < CK * CK; idx += blockDim.x) {
        const int i = idx / CK + 1, j = idx % CK + 1;
        if (i != j) {
            float sq = 0.f;
#pragma unroll
            for (int e = 0; e < E_DIM; e++) {
                const float d = lmean[i * E_DIM + e] - lmean[j * E_DIM + e];
                sq += d * d;
            }
            const float dm = sqrtf(sq);
            const float h = fmaxf(3.0f - dm, 0.f);   // 2*DELTA_DIST = 3
            acc += h * h;
        }
    }
    acc *= 1.0f / (float)(CK * (CK - 1));            // BETA = 1

    float racc = 0.f;
    for (int c = tid + 1; c < C_CLS; c += blockDim.x) {
        float sq = 0.f;
#pragma unroll
        for (int e = 0; e < E_DIM; e++) {
            const float m = lmean[c * E_DIM + e];
            sq += m * m;
        }
        racc += sqrtf(sq);
    }
    acc += 0.001f * racc / (float)CK;                // GAMMA = 0.001

    red[tid] = acc;
    __syncthreads();
    for (int s = blockDim.x / 2; s > 0; s >>= 1) {
        if (tid < s) red[tid] += red[tid + s];
        __syncthreads();
    }
    if (tid == 0) atomicAdd(ws + LOSS_OFF, red[0]);
}

// ---------------- Kernel 3: variance (pull) term ----------------
// Same forced-MLP structure: sched_barrier(0) after the load batch (the e-loop
// consumer chain is sequential, so without the fence the scheduler interleaves
// one load per subtract -> serialized latency, ~100 us hidden in prior rounds).
__global__ __launch_bounds__(256, 2) void k_var(const float* __restrict__ emb,
                                                const int* __restrict__ target,
                                                float* __restrict__ ws) {
    __shared__ float lmean[C_CLS * MSTRIDE];
    __shared__ float lw[C_CLS];
    __shared__ float wred[4];
    const int n = blockIdx.y, tid = threadIdx.x;

    const float* gmean = ws + MEAN_OFF + n * C_CLS * E_DIM;
    const float* gcnt  = ws + CNT_OFF + n * C_CLS;
    for (int i = tid; i < C_CLS * E_DIM; i += 256) {
        const int c = i >> 4, e = i & 15;
        lmean[c * MSTRIDE + e] = gmean[i];
    }
    if (tid < C_CLS) {
        const float cnt = gcnt[tid];
        lw[tid] = (tid != 0 && cnt > 0.f) ? 1.0f / (cnt * (float)CK) : 0.f;
    }
    __syncthreads();

    float acc = 0.f;
    const int g = blockIdx.x * 256 + tid;
    if (g < G_PIX) {
        const int4 lb = ((const int4*)target)[(size_t)n * G_PIX + g];
        const float4* emb4 = (const float4*)emb + (size_t)n * E_DIM * G_PIX;
        float4 v[E_DIM];
#pragma unroll
        for (int e = 0; e < E_DIM; e++) v[e] = emb4[(size_t)e * G_PIX + g];

        __builtin_amdgcn_sched_barrier(0);   // all 17 loads in flight before compute

        const int bx = lb.x * MSTRIDE, by = lb.y * MSTRIDE;
        const int bz = lb.z * MSTRIDE, bw = lb.w * MSTRIDE;
        float sx = 0.f, sy = 0.f, sz = 0.f, sw = 0.f;
#pragma unroll
        for (int e = 0; e < E_DIM; e++) {
            float d;
            d = v[e].x - lmean[bx + e]; sx += d * d;
            d = v[e].y - lmean[by + e]; sy += d * d;
            d = v[e].z - lmean[bz + e]; sz += d * d;
            d = v[e].w - lmean[bw + e]; sw += d * d;
        }
        float h;
        h = fmaxf(sqrtf(sx) - 0.5f, 0.f); acc += h * h * lw[lb.x];  // DELTA_VAR = 0.5
        h = fmaxf(sqrtf(sy) - 0.5f, 0.f); acc += h * h * lw[lb.y];
        h = fmaxf(sqrtf(sz) - 0.5f, 0.f); acc += h * h * lw[lb.z];
        h = fmaxf(sqrtf(sw) - 0.5f, 0.f); acc += h * h * lw[lb.w];  // lw[0]=0 masks IGNORE
    }

    // wave shuffle reduction, then cross-wave via 4 LDS slots
#pragma unroll
    for (int off = 32; off > 0; off >>= 1) acc += __shfl_down(acc, off, 64);
    if ((tid & 63) == 0) wred[tid >> 6] = acc;
    __syncthreads();
    if (tid == 0) atomicAdd(ws + LOSS_OFF, wred[0] + wred[1] + wred[2] + wred[3]);
}

// ---------------- Kernel 4: finalize ----------------
__global__ void k_fin(const float* __restrict__ ws, float* __restrict__ out) {
    out[0] = ws[LOSS_OFF] * 0.25f;  // mean over 4 images
}

extern "C" void kernel_launch(void* const* d_in, const int* in_sizes, int n_in,
                              void* d_out, int out_size, void* d_ws, size_t ws_size,
                              hipStream_t stream) {
    const float* emb = (const float*)d_in[0];
    const int* target = (const int*)d_in[1];
    float* out = (float*)d_out;
    float* ws = (float*)d_ws;

    hipMemsetAsync(d_ws, 0, WS_FLOATS * sizeof(float), stream);

    dim3 gp((G_PIX + 255) / 256, N_IMG);   // 313 x 4 blocks
    k_sums<<<gp, 256, 0, stream>>>(emb, target, ws);
    k_means_dist<<<N_IMG, 256, 0, stream>>>(ws);
    k_var<<<gp, 256, 0, stream>>>(emb, target, ws);
    k_fin<<<1, 1, 0, stream>>>(ws, out);
}